// Round 3
// baseline (376.485 us; speedup 1.0000x reference)
//
#include <hip/hip_runtime.h>
#include <hip/hip_bf16.h>
#include <cstdint>
#include <cstddef>

#define B_ 4
#define S_ 2048
#define T_ 2048
#define C_ 256
#define NEG_INF (-INFINITY)

typedef __attribute__((ext_vector_type(8)))  __bf16 bf16x8;
typedef __attribute__((ext_vector_type(4)))  __bf16 bf16x4;
typedef __attribute__((ext_vector_type(16))) float  f32x16;

// C/D layout for mfma_f32_32x32x16_bf16 (m74/m101): col=lane&31,
// row = (reg&3) + 8*(reg>>2) + 4*(lane>>5)
#define ROWPAT(r, lh) (((r) & 3) + 8 * ((r) >> 2) + 4 * (lh))

// ---------------------------------------------------------------------------
// Mask canonicalization (byte-bool vs 4-byte detection via element 1)
// ---------------------------------------------------------------------------
__global__ void build_masks_kernel(const void* __restrict__ src_mask,
                                   const void* __restrict__ tgt_mask,
                                   int* __restrict__ smask, int* __restrict__ tmask) {
    int i = blockIdx.x * blockDim.x + threadIdx.x;
    const unsigned char* sb = (const unsigned char*)src_mask;
    const unsigned char* tb = (const unsigned char*)tgt_mask;
    bool s_is_byte = (sb[1] != 0);
    bool t_is_byte = (tb[1] != 0);
    if (i < B_ * S_)
        smask[i] = s_is_byte ? (sb[i] != 0) : (((const int*)src_mask)[i] != 0);
    if (i < B_ * T_)
        tmask[i] = t_is_byte ? (tb[i] != 0) : (((const int*)tgt_mask)[i] != 0);
}

// ---------------------------------------------------------------------------
// f32 -> (hi, lo) bf16 split, RNE both stages. x ~= hi + lo, rel err ~2^-18.
// ---------------------------------------------------------------------------
__global__ __launch_bounds__(256) void split_kernel(
    const float* __restrict__ in, __bf16* __restrict__ h, __bf16* __restrict__ l,
    int n4)
{
    for (int i = blockIdx.x * blockDim.x + threadIdx.x; i < n4;
         i += gridDim.x * blockDim.x) {
        float4 x = ((const float4*)in)[i];
        float xs[4] = {x.x, x.y, x.z, x.w};
        bf16x4 hv, lv;
        #pragma unroll
        for (int j = 0; j < 4; ++j) {
            __bf16 hh = (__bf16)xs[j];
            hv[j] = hh;
            lv[j] = (__bf16)(xs[j] - (float)hh);
        }
        ((bf16x4*)h)[i] = hv;
        ((bf16x4*)l)[i] = lv;
    }
}

// ---------------------------------------------------------------------------
// 12 MFMAs (3-product bf16x3) for one k-step, 2x2 fragments
// ---------------------------------------------------------------------------
#define MFMA3(i, j)                                                              \
    acc[i][j] = __builtin_amdgcn_mfma_f32_32x32x16_bf16(ah[i], bh[j], acc[i][j], 0, 0, 0); \
    acc[i][j] = __builtin_amdgcn_mfma_f32_32x32x16_bf16(ah[i], bl[j], acc[i][j], 0, 0, 0); \
    acc[i][j] = __builtin_amdgcn_mfma_f32_32x32x16_bf16(al[i], bh[j], acc[i][j], 0, 0, 0);

// ---------------------------------------------------------------------------
// Projection GEMM (MFMA, no LDS): P[m,n] = (1/16) * sum_k F[m,k] * W[n,k]
// Tile 128x128, 4 waves 2x2, each wave 64x64 (2x2 frags of 32x32x16).
// Epilogue re-splits the f32 result to hi/lo bf16.
// ---------------------------------------------------------------------------
__global__ __launch_bounds__(256) void proj_kernel(
    const __bf16* __restrict__ Fh, const __bf16* __restrict__ Fl,
    const __bf16* __restrict__ Wh, const __bf16* __restrict__ Wl,
    __bf16* __restrict__ Ph, __bf16* __restrict__ Pl)
{
    const int n0 = blockIdx.x * 128, m0 = blockIdx.y * 128;
    const int w = threadIdx.x >> 6, lane = threadIdx.x & 63;
    const int wr = w >> 1, wc = w & 1;
    const int lr = lane & 31, lh = lane >> 5;

    const size_t aoff0 = (size_t)(m0 + 64 * wr + lr) * C_ + 8 * lh;
    const size_t aoff1 = aoff0 + 32 * C_;
    const size_t boff0 = (size_t)(n0 + 64 * wc + lr) * C_ + 8 * lh;
    const size_t boff1 = boff0 + 32 * C_;

    f32x16 acc[2][2] = {};
    #pragma unroll 2
    for (int ks = 0; ks < 16; ++ks) {
        const int kk = ks * 16;
        bf16x8 ah[2], al[2], bh[2], bl[2];
        ah[0] = *(const bf16x8*)(Fh + aoff0 + kk);
        ah[1] = *(const bf16x8*)(Fh + aoff1 + kk);
        al[0] = *(const bf16x8*)(Fl + aoff0 + kk);
        al[1] = *(const bf16x8*)(Fl + aoff1 + kk);
        bh[0] = *(const bf16x8*)(Wh + boff0 + kk);
        bh[1] = *(const bf16x8*)(Wh + boff1 + kk);
        bl[0] = *(const bf16x8*)(Wl + boff0 + kk);
        bl[1] = *(const bf16x8*)(Wl + boff1 + kk);
        MFMA3(0, 0) MFMA3(0, 1) MFMA3(1, 0) MFMA3(1, 1)
    }

    #pragma unroll
    for (int i = 0; i < 2; ++i)
        #pragma unroll
        for (int j = 0; j < 2; ++j)
            #pragma unroll
            for (int r = 0; r < 16; ++r) {
                float v = acc[i][j][r] * 0.0625f;
                __bf16 hh = (__bf16)v;
                int row = m0 + 64 * wr + 32 * i + ROWPAT(r, lh);
                int col = n0 + 64 * wc + 32 * j + lr;
                Ph[(size_t)row * C_ + col] = hh;
                Pl[(size_t)row * C_ + col] = (__bf16)(v - (float)hh);
            }
}

// ---------------------------------------------------------------------------
// sim GEMM (MFMA bf16x3, no LDS tiles), computed per batch.
// MODE 0: fused masked softmax-stat partials -> rowpart/colpart (no sim write)
// MODE 1: conf epilogue: conf = exp(2x-cm-rm)*invc*invr, write conf,
//         atomicMax row/col conf maxima. Mainloop identical -> x bit-identical.
// ---------------------------------------------------------------------------
template <int MODE>
__global__ __launch_bounds__(256) void simgemm_kernel(
    const __bf16* __restrict__ Ah_, const __bf16* __restrict__ Al_,
    const __bf16* __restrict__ Bh_, const __bf16* __restrict__ Bl_,
    const int* __restrict__ smask, const int* __restrict__ tmask,
    float2* __restrict__ rowpart, float2* __restrict__ colpart,
    const float2* __restrict__ rowstats, const float2* __restrict__ colstats,
    float* __restrict__ conf, unsigned* __restrict__ rowconfmax,
    unsigned* __restrict__ colconfmax)
{
    const int b = blockIdx.z;
    const int n0 = blockIdx.x * 128, m0 = blockIdx.y * 128;
    const int w = threadIdx.x >> 6, lane = threadIdx.x & 63;
    const int wr = w >> 1, wc = w & 1;
    const int lr = lane & 31, lh = lane >> 5;

    __shared__ int smask_lds[128], tmask_lds[128];
    __shared__ float2 rstat_lds[128], cstat_lds[128];
    if (threadIdx.x < 128) {
        smask_lds[threadIdx.x] = smask[b * S_ + m0 + threadIdx.x];
        if (MODE == 1) rstat_lds[threadIdx.x] = rowstats[b * S_ + m0 + threadIdx.x];
    } else {
        int t = threadIdx.x - 128;
        tmask_lds[t] = tmask[b * T_ + n0 + t];
        if (MODE == 1) cstat_lds[t] = colstats[b * T_ + n0 + t];
    }
    __syncthreads();

    const __bf16* Ah = Ah_ + (size_t)b * S_ * C_;
    const __bf16* Al = Al_ + (size_t)b * S_ * C_;
    const __bf16* Bh = Bh_ + (size_t)b * T_ * C_;
    const __bf16* Bl = Bl_ + (size_t)b * T_ * C_;

    const size_t aoff0 = (size_t)(m0 + 64 * wr + lr) * C_ + 8 * lh;
    const size_t aoff1 = aoff0 + 32 * C_;
    const size_t boff0 = (size_t)(n0 + 64 * wc + lr) * C_ + 8 * lh;
    const size_t boff1 = boff0 + 32 * C_;

    f32x16 acc[2][2] = {};
    #pragma unroll 2
    for (int ks = 0; ks < 16; ++ks) {
        const int kk = ks * 16;
        bf16x8 ah[2], al[2], bh[2], bl[2];
        ah[0] = *(const bf16x8*)(Ah + aoff0 + kk);
        ah[1] = *(const bf16x8*)(Ah + aoff1 + kk);
        al[0] = *(const bf16x8*)(Al + aoff0 + kk);
        al[1] = *(const bf16x8*)(Al + aoff1 + kk);
        bh[0] = *(const bf16x8*)(Bh + boff0 + kk);
        bh[1] = *(const bf16x8*)(Bh + boff1 + kk);
        bl[0] = *(const bf16x8*)(Bl + boff0 + kk);
        bl[1] = *(const bf16x8*)(Bl + boff1 + kk);
        MFMA3(0, 0) MFMA3(0, 1) MFMA3(1, 0) MFMA3(1, 1)
    }

    // x = sim/TEMP = acc * 10  (identical op in both MODEs -> bit-identical)
    if (MODE == 0) {
        const int tm0 = tmask_lds[64 * wc + lr];
        const int tm1 = tmask_lds[64 * wc + 32 + lr];
        // ---- row partials: masked by tmask, reduce over this block's cols ----
        #pragma unroll
        for (int i = 0; i < 2; ++i) {
            #pragma unroll
            for (int r = 0; r < 16; ++r) {
                float v0 = tm0 ? acc[i][0][r] * 10.f : NEG_INF;
                float v1 = tm1 ? acc[i][1][r] * 10.f : NEG_INF;
                float m = fmaxf(v0, v1);
                #pragma unroll
                for (int off = 1; off <= 16; off <<= 1)
                    m = fmaxf(m, __shfl_xor(m, off));
                float e = 0.f;
                if (m > NEG_INF) e = __expf(v0 - m) + __expf(v1 - m);
                #pragma unroll
                for (int off = 1; off <= 16; off <<= 1)
                    e += __shfl_xor(e, off);
                if (lr == 0) {
                    int row = m0 + 64 * wr + 32 * i + ROWPAT(r, lh);
                    rowpart[((size_t)(b * S_ + row)) * 32 + (n0 >> 6) + wc] =
                        make_float2(m, e);
                }
            }
        }
        // ---- col partials: masked by smask, reduce over this wave's 64 rows ----
        #pragma unroll
        for (int j = 0; j < 2; ++j) {
            float m = NEG_INF;
            #pragma unroll
            for (int i = 0; i < 2; ++i)
                #pragma unroll
                for (int r = 0; r < 16; ++r) {
                    int sm = smask_lds[64 * wr + 32 * i + ROWPAT(r, lh)];
                    float x = sm ? acc[i][j][r] * 10.f : NEG_INF;
                    m = fmaxf(m, x);
                }
            m = fmaxf(m, __shfl_xor(m, 32));
            float e = 0.f;
            if (m > NEG_INF) {
                #pragma unroll
                for (int i = 0; i < 2; ++i)
                    #pragma unroll
                    for (int r = 0; r < 16; ++r) {
                        int sm = smask_lds[64 * wr + 32 * i + ROWPAT(r, lh)];
                        float x = sm ? acc[i][j][r] * 10.f : NEG_INF;
                        e += __expf(x - m);   // exp(-inf)=0 for masked
                    }
            }
            e += __shfl_xor(e, 32);
            if (lh == 0) {
                int col = n0 + 64 * wc + 32 * j + lr;
                colpart[((size_t)(b * T_ + col)) * 32 + (m0 >> 6) + wr] =
                    make_float2(m, e);
            }
        }
    } else {
        const int tm0 = tmask_lds[64 * wc + lr];
        const int tm1 = tmask_lds[64 * wc + 32 + lr];
        float2 cst0 = cstat_lds[64 * wc + lr];
        float2 cst1 = cstat_lds[64 * wc + 32 + lr];
        const float cm0 = cst0.x, invc0 = 1.f / cst0.y;
        const float cm1 = cst1.x, invc1 = 1.f / cst1.y;
        float* confb = conf + (size_t)b * S_ * T_;
        float cmax0 = 0.f, cmax1 = 0.f;
        #pragma unroll
        for (int i = 0; i < 2; ++i) {
            #pragma unroll
            for (int r = 0; r < 16; ++r) {
                int row_l = 64 * wr + 32 * i + ROWPAT(r, lh);
                float2 rst = rstat_lds[row_l];
                int sm = smask_lds[row_l];
                float rm = rst.x, invr = 1.f / rst.y;
                float v0 = acc[i][0][r] * 10.f;
                float v1 = acc[i][1][r] * 10.f;
                float c0 = (sm && tm0)
                    ? __expf(2.f * v0 - cm0 - rm) * (invc0 * invr) : 0.f;
                float c1 = (sm && tm1)
                    ? __expf(2.f * v1 - cm1 - rm) * (invc1 * invr) : 0.f;
                int row_g = m0 + row_l;
                int col0 = n0 + 64 * wc + lr;
                confb[(size_t)row_g * T_ + col0]      = c0;
                confb[(size_t)row_g * T_ + col0 + 32] = c1;
                float rmx = fmaxf(c0, c1);
                #pragma unroll
                for (int off = 1; off <= 16; off <<= 1)
                    rmx = fmaxf(rmx, __shfl_xor(rmx, off));
                if (lr == 0)
                    atomicMax(&rowconfmax[b * S_ + row_g], __float_as_uint(rmx));
                cmax0 = fmaxf(cmax0, c0);
                cmax1 = fmaxf(cmax1, c1);
            }
        }
        cmax0 = fmaxf(cmax0, __shfl_xor(cmax0, 32));
        cmax1 = fmaxf(cmax1, __shfl_xor(cmax1, 32));
        if (lh == 0) {
            int col0 = n0 + 64 * wc + lr;
            atomicMax(&colconfmax[b * T_ + col0],      __float_as_uint(cmax0));
            atomicMax(&colconfmax[b * T_ + col0 + 32], __float_as_uint(cmax1));
        }
    }
}

// ---------------------------------------------------------------------------
// Merge 32 (max,sumexp) partials per row/col
// ---------------------------------------------------------------------------
__global__ __launch_bounds__(256) void combine_kernel(
    const float2* __restrict__ part, float2* __restrict__ stats, int nrow)
{
    int r = blockIdx.x * 256 + threadIdx.x;
    if (r >= nrow) return;
    const float2* p = part + (size_t)r * 32;
    float M = NEG_INF;
    float2 v[32];
    #pragma unroll
    for (int q = 0; q < 16; ++q) {
        float4 f = *(const float4*)(p + q * 2);
        v[2 * q]     = make_float2(f.x, f.y);
        v[2 * q + 1] = make_float2(f.z, f.w);
    }
    #pragma unroll
    for (int q = 0; q < 32; ++q) M = fmaxf(M, v[q].x);
    float SS = 0.f;
    if (M > NEG_INF) {
        #pragma unroll
        for (int q = 0; q < 32; ++q) SS += v[q].y * __expf(v[q].x - M);
    }
    stats[r] = make_float2(M, SS);
}

// ---------------------------------------------------------------------------
// mask = conf > 0.2 && conf == rowmax && conf == colmax  (0.0/1.0 floats)
// ---------------------------------------------------------------------------
__global__ __launch_bounds__(256) void maskout_kernel(
    const float* __restrict__ conf,
    const unsigned* __restrict__ rowconfmax, const unsigned* __restrict__ colconfmax,
    float* __restrict__ outmask)
{
    const size_t n4 = (size_t)B_ * S_ * T_ / 4;
    for (size_t i4 = (size_t)blockIdx.x * blockDim.x + threadIdx.x; i4 < n4;
         i4 += (size_t)gridDim.x * blockDim.x) {
        size_t base = i4 * 4;
        int t0  = (int)(base & (T_ - 1));
        int row = (int)(base >> 11);        // b*S + s
        int b   = row >> 11;
        float4 c = *(const float4*)(conf + base);
        float rm = __uint_as_float(rowconfmax[row]);
        const unsigned* cmp = colconfmax + b * T_ + t0;
        float cc[4] = {c.x, c.y, c.z, c.w};
        float o[4];
        #pragma unroll
        for (int j = 0; j < 4; ++j) {
            float cmv = __uint_as_float(cmp[j]);
            o[j] = (cc[j] > 0.2f && cc[j] == rm && cc[j] == cmv) ? 1.f : 0.f;
        }
        *(float4*)(outmask + base) = make_float4(o[0], o[1], o[2], o[3]);
    }
}

extern "C" void kernel_launch(void* const* d_in, const int* in_sizes, int n_in,
                              void* d_out, int out_size, void* d_ws, size_t ws_size,
                              hipStream_t stream)
{
    const float* src_feats = (const float*)d_in[0];
    const float* tgt_feats = (const float*)d_in[1];
    const void*  src_mask  = d_in[2];
    const void*  tgt_mask  = d_in[3];
    const float* W         = (const float*)d_in[4];

    float* conf    = (float*)d_out;                      // [B,S,T] final conf
    char*  maskreg = (char*)d_out + (size_t)B_ * S_ * T_ * 4;  // 64MB scratch, mask last

    // scratch layout inside mask region (re-written every call; clobbered by maskout)
    const size_t MB = 1024 * 1024;
    __bf16* srcf_h = (__bf16*)(maskreg + 0 * MB);
    __bf16* srcf_l = (__bf16*)(maskreg + 4 * MB);
    __bf16* tgtf_h = (__bf16*)(maskreg + 8 * MB);
    __bf16* tgtf_l = (__bf16*)(maskreg + 12 * MB);
    __bf16* srcp_h = (__bf16*)(maskreg + 16 * MB);
    __bf16* srcp_l = (__bf16*)(maskreg + 20 * MB);
    __bf16* tgtp_h = (__bf16*)(maskreg + 24 * MB);
    __bf16* tgtp_l = (__bf16*)(maskreg + 28 * MB);
    __bf16* W_h    = (__bf16*)(maskreg + 32 * MB);
    __bf16* W_l    = (__bf16*)(maskreg + 32 * MB + 128 * 1024);
    float2* rowpart = (float2*)(maskreg + 33 * MB);      // B*S*32 float2 = 2MB
    float2* colpart = (float2*)(maskreg + 35 * MB);      // B*T*32 float2 = 2MB

    // small scratch in d_ws (~256KB)
    float2*   rowstats   = (float2*)d_ws;                    // B*S
    float2*   colstats   = rowstats + B_ * S_;               // B*T
    unsigned* rowconfmax = (unsigned*)(colstats + B_ * T_);  // B*S
    unsigned* colconfmax = rowconfmax + B_ * S_;             // B*T
    int*      smask      = (int*)(colconfmax + B_ * T_);     // B*S
    int*      tmask      = smask + B_ * S_;                  // B*T

    hipMemsetAsync(rowconfmax, 0, (size_t)(B_ * S_ + B_ * T_) * sizeof(unsigned),
                   stream);
    build_masks_kernel<<<(B_ * S_ + 255) / 256, 256, 0, stream>>>(
        src_mask, tgt_mask, smask, tmask);

    // f32 -> hi/lo bf16 splits
    split_kernel<<<1024, 256, 0, stream>>>(src_feats, srcf_h, srcf_l,
                                           B_ * S_ * C_ / 4);
    split_kernel<<<1024, 256, 0, stream>>>(tgt_feats, tgtf_h, tgtf_l,
                                           B_ * T_ * C_ / 4);
    split_kernel<<<64, 256, 0, stream>>>(W, W_h, W_l, C_ * C_ / 4);

    // projections (MFMA bf16x3), epilogue folds /16 and re-splits to hi/lo
    proj_kernel<<<dim3(C_ / 128, B_ * S_ / 128), 256, 0, stream>>>(
        srcf_h, srcf_l, W_h, W_l, srcp_h, srcp_l);
    proj_kernel<<<dim3(C_ / 128, B_ * T_ / 128), 256, 0, stream>>>(
        tgtf_h, tgtf_l, W_h, W_l, tgtp_h, tgtp_l);

    // pass 1: GEMM + fused masked softmax-stat partials (no sim materialization)
    simgemm_kernel<0><<<dim3(T_ / 128, S_ / 128, B_), 256, 0, stream>>>(
        srcp_h, srcp_l, tgtp_h, tgtp_l, smask, tmask, rowpart, colpart,
        nullptr, nullptr, nullptr, nullptr, nullptr);

    combine_kernel<<<(B_ * S_ + 255) / 256, 256, 0, stream>>>(
        rowpart, rowstats, B_ * S_);
    combine_kernel<<<(B_ * T_ + 255) / 256, 256, 0, stream>>>(
        colpart, colstats, B_ * T_);

    // pass 2: identical GEMM + conf epilogue (write conf + conf maxima)
    simgemm_kernel<1><<<dim3(T_ / 128, S_ / 128, B_), 256, 0, stream>>>(
        srcp_h, srcp_l, tgtp_h, tgtp_l, smask, tmask, nullptr, nullptr,
        rowstats, colstats, conf, rowconfmax, colconfmax);

    maskout_kernel<<<4096, 256, 0, stream>>>(conf, rowconfmax, colconfmax,
                                             (float*)maskreg);
}

// Round 4
// 304.013 us; speedup vs baseline: 1.2384x; 1.2384x over previous
//
#include <hip/hip_runtime.h>
#include <hip/hip_bf16.h>
#include <cstdint>
#include <cstddef>

#define B_ 4
#define S_ 2048
#define T_ 2048
#define C_ 256
#define K2_ 512                       // interleaved hi/lo K
#define NEG_INF (-INFINITY)

typedef __attribute__((ext_vector_type(8)))  __bf16 bf16x8;
typedef __attribute__((ext_vector_type(16))) float  f32x16;

// C/D layout for mfma_f32_32x32x16_bf16 (m74/m101): col=lane&31,
// row = (reg&3) + 8*(reg>>2) + 4*(lane>>5)
#define ROWPAT(r, lh) (((r) & 3) + 8 * ((r) >> 2) + 4 * (lh))

typedef __attribute__((address_space(3))) unsigned       as3_u32;
typedef __attribute__((address_space(1))) const unsigned as1_u32;

__device__ __forceinline__ void gload16(const void* g, void* l) {
    __builtin_amdgcn_global_load_lds((as1_u32*)g, (as3_u32*)l, 16, 0, 0);
}

// f32 -> packed (hi bf16 | lo bf16) u32, RNE both stages; hi at low halfword
__device__ __forceinline__ unsigned pack_hl(float v) {
    __bf16 h = (__bf16)v;
    __bf16 l = (__bf16)(v - (float)h);
    unsigned short hu = __builtin_bit_cast(unsigned short, h);
    unsigned short lu = __builtin_bit_cast(unsigned short, l);
    return (unsigned)hu | ((unsigned)lu << 16);
}

// ---------------------------------------------------------------------------
// Mask canonicalization (byte-bool vs 4-byte detection via element 1)
// ---------------------------------------------------------------------------
__global__ void build_masks_kernel(const void* __restrict__ src_mask,
                                   const void* __restrict__ tgt_mask,
                                   int* __restrict__ smask, int* __restrict__ tmask) {
    int i = blockIdx.x * blockDim.x + threadIdx.x;
    const unsigned char* sb = (const unsigned char*)src_mask;
    const unsigned char* tb = (const unsigned char*)tgt_mask;
    bool s_is_byte = (sb[1] != 0);
    bool t_is_byte = (tb[1] != 0);
    if (i < B_ * S_)
        smask[i] = s_is_byte ? (sb[i] != 0) : (((const int*)src_mask)[i] != 0);
    if (i < B_ * T_)
        tmask[i] = t_is_byte ? (tb[i] != 0) : (((const int*)tgt_mask)[i] != 0);
}

// ---------------------------------------------------------------------------
// f32 -> k-interleaved hi/lo bf16 (one u32 per input float)
// ---------------------------------------------------------------------------
__global__ __launch_bounds__(256) void split_kernel(
    const float* __restrict__ in, unsigned* __restrict__ out, int n4)
{
    for (int i = blockIdx.x * blockDim.x + threadIdx.x; i < n4;
         i += gridDim.x * blockDim.x) {
        float4 x = ((const float4*)in)[i];
        uint4 o;
        o.x = pack_hl(x.x); o.y = pack_hl(x.y);
        o.z = pack_hl(x.z); o.w = pack_hl(x.w);
        ((uint4*)out)[i] = o;
    }
}

// ---------------------------------------------------------------------------
// Unified 256x256-tile MFMA GEMM on k-interleaved hi/lo operands.
//   out = sum_k A[m,k]*B[n,k]  (full (Ah+Al)(Bh+Bl) via normal + pair-swapped)
// 512 thr = 8 waves (2 m x 4 n), wave = 128x64 = 4x2 frags of 32x32x16.
// Double-buffered LDS, global_load_lds w=16, XOR-swizzled source/reads.
// MODE 0: sim pass 1 -> masked softmax row/col partials (no big write)
// MODE 1: sim pass 2 -> conf = exp(2x-cm-rm)/(cs*rs), + row/col conf maxima
// MODE 2: projection -> P2out packed hi/lo (scale 1/16)
// ---------------------------------------------------------------------------
template <int MODE>
__global__ __launch_bounds__(512, 2) void simgemm_kernel(
    const __bf16* __restrict__ A2g, const __bf16* __restrict__ B2g,
    const int* __restrict__ smask, const int* __restrict__ tmask,
    float2* __restrict__ rowpart, float2* __restrict__ colpart,
    const float2* __restrict__ rowstats, const float2* __restrict__ colstats,
    float* __restrict__ conf, unsigned* __restrict__ rowconfmax,
    unsigned* __restrict__ colconfmax, unsigned* __restrict__ P2out)
{
    __shared__ char lds[2 * 65536 + 256 * 4 * 2 + 256 * 8 * 2];
    char* bufs = lds;
    int*    smask_lds = (int*)(lds + 131072);
    int*    tmask_lds = smask_lds + 256;
    float2* rstat_lds = (float2*)(tmask_lds + 256);
    float2* cstat_lds = rstat_lds + 256;

    const int tid = threadIdx.x;
    const int w = tid >> 6, lane = tid & 63;
    const int wr = w >> 2, wc = w & 3;     // wave grid 2 x 4
    const int lr = lane & 31, lh = lane >> 5;

    int b = 0, m0, n0;
    const __bf16 *Ab, *Bb;
    if (MODE == 2) {
        m0 = blockIdx.x * 256; n0 = 0;
        Ab = A2g; Bb = B2g;
    } else {
        // bijective XCD remap: 32 consecutive tiles per XCD -> 3MB panel set in L2
        int lin = (blockIdx.x & 7) * 32 + (blockIdx.x >> 3);
        b = lin >> 6;
        int r = lin & 63;
        m0 = (r >> 3) * 256;
        n0 = (r & 7) * 256;
        Ab = A2g + (size_t)b * S_ * K2_;
        Bb = B2g + (size_t)b * T_ * K2_;
        if (tid < 256) {
            smask_lds[tid] = smask[b * S_ + m0 + tid];
            if (MODE == 1) rstat_lds[tid] = rowstats[b * S_ + m0 + tid];
        } else {
            int t = tid - 256;
            tmask_lds[t] = tmask[b * T_ + n0 + t];
            if (MODE == 1) cstat_lds[t] = colstats[b * T_ + n0 + t];
        }
    }

    // stage one BK2=64 slab (A 32KB + B 32KB) with source-side XOR swizzle
    auto stage = [&](int st) {
        char* buf = bufs + (st & 1) * 65536;
        const int kb = st * 64;
        #pragma unroll
        for (int q = 0; q < 4; ++q) {
            int i = q * 512 + tid;            // dest 16B slot (linear)
            int row = i >> 3, c = i & 7;
            int sc = c ^ (row & 7);           // involution: source pre-swizzle
            gload16(Ab + (size_t)(m0 + row) * K2_ + kb + sc * 8,
                    buf + (q * 512 + w * 64) * 16);
        }
        char* bufB = buf + 32768;
        #pragma unroll
        for (int q = 0; q < 4; ++q) {
            int i = q * 512 + tid;
            int row = i >> 3, c = i & 7;
            int sc = c ^ (row & 7);
            gload16(Bb + (size_t)(n0 + row) * K2_ + kb + sc * 8,
                    bufB + (q * 512 + w * 64) * 16);
        }
    };

    f32x16 acc[4][2] = {};
    stage(0);
    __syncthreads();
    for (int st = 0; st < 8; ++st) {
        if (st < 7) stage(st + 1);
        const char* buf  = bufs + (st & 1) * 65536;
        const char* bufB = buf + 32768;
        #pragma unroll
        for (int ks = 0; ks < 4; ++ks) {
            const int cs = ks * 2 + lh;
            bf16x8 a[4], bv[2], bs[2];
            #pragma unroll
            for (int fi = 0; fi < 4; ++fi) {
                int row = wr * 128 + fi * 32 + lr;
                a[fi] = *(const bf16x8*)(buf + row * 128 + ((cs ^ (row & 7)) * 16));
            }
            #pragma unroll
            for (int fj = 0; fj < 2; ++fj) {
                int row = wc * 64 + fj * 32 + lr;
                bv[fj] = *(const bf16x8*)(bufB + row * 128 + ((cs ^ (row & 7)) * 16));
                bs[fj] = __builtin_shufflevector(bv[fj], bv[fj], 1, 0, 3, 2, 5, 4, 7, 6);
            }
            #pragma unroll
            for (int fi = 0; fi < 4; ++fi)
                #pragma unroll
                for (int fj = 0; fj < 2; ++fj)
                    acc[fi][fj] = __builtin_amdgcn_mfma_f32_32x32x16_bf16(
                        a[fi], bv[fj], acc[fi][fj], 0, 0, 0);   // hh + ll
            #pragma unroll
            for (int fi = 0; fi < 4; ++fi)
                #pragma unroll
                for (int fj = 0; fj < 2; ++fj)
                    acc[fi][fj] = __builtin_amdgcn_mfma_f32_32x32x16_bf16(
                        a[fi], bs[fj], acc[fi][fj], 0, 0, 0);   // hl + lh
        }
        __syncthreads();
    }

    if (MODE == 2) {
        #pragma unroll
        for (int fi = 0; fi < 4; ++fi)
            #pragma unroll
            for (int fj = 0; fj < 2; ++fj)
                #pragma unroll
                for (int r = 0; r < 16; ++r) {
                    int row = m0 + wr * 128 + fi * 32 + ROWPAT(r, lh);
                    int col = wc * 64 + fj * 32 + lr;
                    P2out[(size_t)row * 256 + col] = pack_hl(acc[fi][fj][r] * 0.0625f);
                }
        return;
    }

    if (MODE == 0) {
        const int tm0 = tmask_lds[wc * 64 + lr];
        const int tm1 = tmask_lds[wc * 64 + 32 + lr];
        // row partials over this block's 256 cols (tmask'd)
        #pragma unroll
        for (int fi = 0; fi < 4; ++fi)
            #pragma unroll
            for (int r = 0; r < 16; ++r) {
                float v0 = tm0 ? acc[fi][0][r] * 10.f : NEG_INF;
                float v1 = tm1 ? acc[fi][1][r] * 10.f : NEG_INF;
                float m = fmaxf(v0, v1);
                #pragma unroll
                for (int off = 1; off <= 16; off <<= 1)
                    m = fmaxf(m, __shfl_xor(m, off));
                float e = 0.f;
                if (m > NEG_INF) e = __expf(v0 - m) + __expf(v1 - m);
                #pragma unroll
                for (int off = 1; off <= 16; off <<= 1)
                    e += __shfl_xor(e, off);
                if (lr == 0) {
                    int row = m0 + wr * 128 + fi * 32 + ROWPAT(r, lh);
                    rowpart[((size_t)(b * S_ + row)) * 32 + (n0 >> 6) + wc] =
                        make_float2(m, e);
                }
            }
        // col partials over this wave's 128 rows (smask'd)
        #pragma unroll
        for (int fj = 0; fj < 2; ++fj) {
            float m = NEG_INF;
            #pragma unroll
            for (int fi = 0; fi < 4; ++fi)
                #pragma unroll
                for (int r = 0; r < 16; ++r) {
                    int rl = wr * 128 + fi * 32 + ROWPAT(r, lh);
                    float x = smask_lds[rl] ? acc[fi][fj][r] * 10.f : NEG_INF;
                    m = fmaxf(m, x);
                }
            m = fmaxf(m, __shfl_xor(m, 32));
            float e = 0.f;
            if (m > NEG_INF) {
                #pragma unroll
                for (int fi = 0; fi < 4; ++fi)
                    #pragma unroll
                    for (int r = 0; r < 16; ++r) {
                        int rl = wr * 128 + fi * 32 + ROWPAT(r, lh);
                        float x = smask_lds[rl] ? acc[fi][fj][r] * 10.f : NEG_INF;
                        e += __expf(x - m);
                    }
            }
            e += __shfl_xor(e, 32);
            if (lh == 0) {
                int col = n0 + wc * 64 + fj * 32 + lr;
                colpart[((size_t)(b * T_ + col)) * 16 + (m0 >> 7) + wr] =
                    make_float2(m, e);
            }
        }
        return;
    }

    // MODE 1: conf epilogue
    {
        const int tm0 = tmask_lds[wc * 64 + lr];
        const int tm1 = tmask_lds[wc * 64 + 32 + lr];
        float2 c0 = cstat_lds[wc * 64 + lr];
        float2 c1 = cstat_lds[wc * 64 + 32 + lr];
        const float cm0 = c0.x, ic0 = 1.f / c0.y;
        const float cm1 = c1.x, ic1 = 1.f / c1.y;
        float* confb = conf + (size_t)b * S_ * T_;
        float cmax0 = 0.f, cmax1 = 0.f;
        #pragma unroll
        for (int fi = 0; fi < 4; ++fi)
            #pragma unroll
            for (int r = 0; r < 16; ++r) {
                int rl = wr * 128 + fi * 32 + ROWPAT(r, lh);
                float2 rst = rstat_lds[rl];
                int sm = smask_lds[rl];
                float rm = rst.x, ir = 1.f / rst.y;
                float x0 = acc[fi][0][r] * 10.f;
                float x1 = acc[fi][1][r] * 10.f;
                float cv0 = (sm && tm0)
                    ? __expf(2.f * x0 - cm0 - rm) * (ic0 * ir) : 0.f;
                float cv1 = (sm && tm1)
                    ? __expf(2.f * x1 - cm1 - rm) * (ic1 * ir) : 0.f;
                int rg = m0 + rl;
                int cg = n0 + wc * 64 + lr;
                confb[(size_t)rg * T_ + cg]      = cv0;
                confb[(size_t)rg * T_ + cg + 32] = cv1;
                float rmx = fmaxf(cv0, cv1);
                #pragma unroll
                for (int off = 1; off <= 16; off <<= 1)
                    rmx = fmaxf(rmx, __shfl_xor(rmx, off));
                if (lr == 0)
                    atomicMax(&rowconfmax[b * S_ + rg], __float_as_uint(rmx));
                cmax0 = fmaxf(cmax0, cv0);
                cmax1 = fmaxf(cmax1, cv1);
            }
        cmax0 = fmaxf(cmax0, __shfl_xor(cmax0, 32));
        cmax1 = fmaxf(cmax1, __shfl_xor(cmax1, 32));
        if (lh == 0) {
            int cg = n0 + wc * 64 + lr;
            atomicMax(&colconfmax[b * T_ + cg],      __float_as_uint(cmax0));
            atomicMax(&colconfmax[b * T_ + cg + 32], __float_as_uint(cmax1));
        }
    }
}

// ---------------------------------------------------------------------------
// Merge (max,sumexp) partials
// ---------------------------------------------------------------------------
__global__ __launch_bounds__(256) void combine_kernel(
    const float2* __restrict__ part, float2* __restrict__ stats, int n, int width)
{
    int r = blockIdx.x * 256 + threadIdx.x;
    if (r >= n) return;
    const float2* p = part + (size_t)r * width;
    float M = NEG_INF;
    for (int q = 0; q < width; ++q) M = fmaxf(M, p[q].x);
    float SS = 0.f;
    if (M > NEG_INF)
        for (int q = 0; q < width; ++q) SS += p[q].y * __expf(p[q].x - M);
    stats[r] = make_float2(M, SS);
}

// ---------------------------------------------------------------------------
// mask = conf > 0.2 && conf == rowmax && conf == colmax  (0.0/1.0 floats)
// ---------------------------------------------------------------------------
__global__ __launch_bounds__(256) void maskout_kernel(
    const float* __restrict__ conf,
    const unsigned* __restrict__ rowconfmax, const unsigned* __restrict__ colconfmax,
    float* __restrict__ outmask)
{
    const size_t n4 = (size_t)B_ * S_ * T_ / 4;
    for (size_t i4 = (size_t)blockIdx.x * blockDim.x + threadIdx.x; i4 < n4;
         i4 += (size_t)gridDim.x * blockDim.x) {
        size_t base = i4 * 4;
        int t0  = (int)(base & (T_ - 1));
        int row = (int)(base >> 11);        // b*S + s
        int b   = row >> 11;
        float4 c = *(const float4*)(conf + base);
        float rm = __uint_as_float(rowconfmax[row]);
        const unsigned* cmp = colconfmax + b * T_ + t0;
        float cc[4] = {c.x, c.y, c.z, c.w};
        float o[4];
        #pragma unroll
        for (int j = 0; j < 4; ++j) {
            float cmv = __uint_as_float(cmp[j]);
            o[j] = (cc[j] > 0.2f && cc[j] == rm && cc[j] == cmv) ? 1.f : 0.f;
        }
        *(float4*)(outmask + base) = make_float4(o[0], o[1], o[2], o[3]);
    }
}

extern "C" void kernel_launch(void* const* d_in, const int* in_sizes, int n_in,
                              void* d_out, int out_size, void* d_ws, size_t ws_size,
                              hipStream_t stream)
{
    const float* src_feats = (const float*)d_in[0];
    const float* tgt_feats = (const float*)d_in[1];
    const void*  src_mask  = d_in[2];
    const void*  tgt_mask  = d_in[3];
    const float* W         = (const float*)d_in[4];

    float* conf    = (float*)d_out;
    char*  maskreg = (char*)d_out + (size_t)B_ * S_ * T_ * 4;  // 64MB scratch; mask last

    const size_t MB = 1024 * 1024;
    unsigned* feats2u = (unsigned*)(maskreg);            // 16 MB (src 8MB, tgt 8MB)
    unsigned* P2u     = (unsigned*)(maskreg + 16 * MB);  // 16 MB packed projections
    unsigned* W2u     = (unsigned*)(maskreg + 32 * MB);  // 256 KB
    float2* rowpart   = (float2*)(maskreg + 33 * MB);    // 8192*32*8 = 2 MB
    float2* colpart   = (float2*)(maskreg + 35 * MB);    // 8192*16*8 = 1 MB

    const __bf16* feats2 = (const __bf16*)feats2u;
    const __bf16* W2     = (const __bf16*)W2u;
    const __bf16* P2src  = (const __bf16*)P2u;                   // [B*S][512]
    const __bf16* P2tgt  = P2src + (size_t)B_ * S_ * K2_;        // [B*T][512]

    float2*   rowstats   = (float2*)d_ws;                    // B*S
    float2*   colstats   = rowstats + B_ * S_;               // B*T
    unsigned* rowconfmax = (unsigned*)(colstats + B_ * T_);  // B*S
    unsigned* colconfmax = rowconfmax + B_ * S_;             // B*T
    int*      smask      = (int*)(colconfmax + B_ * T_);     // B*S
    int*      tmask      = smask + B_ * S_;                  // B*T

    hipMemsetAsync(rowconfmax, 0, (size_t)(B_ * S_ + B_ * T_) * sizeof(unsigned),
                   stream);
    build_masks_kernel<<<(B_ * S_ + 255) / 256, 256, 0, stream>>>(
        src_mask, tgt_mask, smask, tmask);

    // f32 -> interleaved hi/lo bf16
    split_kernel<<<2048, 256, 0, stream>>>(src_feats, feats2u, B_ * S_ * C_ / 4);
    split_kernel<<<2048, 256, 0, stream>>>(
        tgt_feats, feats2u + (size_t)B_ * S_ * C_, B_ * T_ * C_ / 4);
    split_kernel<<<64, 256, 0, stream>>>(W, W2u, C_ * C_ / 4);

    // projection: P = (feats @ W^T)/16, output packed hi/lo interleaved
    simgemm_kernel<2><<<(2 * B_ * S_) / 256, 512, 0, stream>>>(
        feats2, W2, nullptr, nullptr, nullptr, nullptr, nullptr, nullptr,
        nullptr, nullptr, nullptr, P2u);

    // pass 1: masked softmax stat partials (no sim materialization)
    simgemm_kernel<0><<<(S_ / 256) * (T_ / 256) * B_, 512, 0, stream>>>(
        P2src, P2tgt, smask, tmask, rowpart, colpart,
        nullptr, nullptr, nullptr, nullptr, nullptr, nullptr);

    combine_kernel<<<(B_ * S_ + 255) / 256, 256, 0, stream>>>(
        rowpart, rowstats, B_ * S_, 32);
    combine_kernel<<<(B_ * T_ + 255) / 256, 256, 0, stream>>>(
        colpart, colstats, B_ * T_, 16);

    // pass 2: identical GEMM + conf epilogue
    simgemm_kernel<1><<<(S_ / 256) * (T_ / 256) * B_, 512, 0, stream>>>(
        P2src, P2tgt, smask, tmask, nullptr, nullptr,
        rowstats, colstats, conf, rowconfmax, colconfmax, nullptr);

    maskout_kernel<<<2048, 256, 0, stream>>>(conf, rowconfmax, colconfmax,
                                             (float*)maskreg);
}